// Round 5
// baseline (227.535 us; speedup 1.0000x reference)
//
#include <hip/hip_runtime.h>

// n=2048 rows, f=32 features. Output row r = [emb[i] (32) | emb[j] (32) | sw[j]],
// i = r>>11, j = r&2047. Output = 2048*2048*65 floats = 1.09 GB, write-BW bound.
//
// v4: i-reuse, load-free steady state. (Resubmit — round 4 bench died with
// UnresponsiveContainer before running; kernel never measured.)
//
// Key observation from v2/v3 (both ~5.2 TB/s vs memset's 6.5): loads and
// stores share ONE in-order vmcnt on CDNA, so any steady-state global load
// whose consumer waits on vmcnt also waits for all OLDER outstanding nt
// stores -> each wave's loop is carried by store-COMPLETION latency.
// fillBuffer (6.5 TB/s @ 3.4 waves/CU) never waits because it never loads.
//
// Fix: exploit reuse. The b-part emb[j0..j0+15] and sw[j0..] are identical
// for EVERY i. Each wave owns one 16-row LDS image (4160 B, single buffer)
// and loops over ICHUNK=16 consecutive i values; per iteration it rewrites
// only the a-part (32 cols) from a preloaded register array va[16], then
// drains 260 float4 with nontemporal stores. Steady state: 8 ds_write +
// 5 ds_read_b128 + 5 stores -- ZERO global loads, vmcnt holds only stores,
// nothing ever waits on it. LDS ordering is free (per-wave in-order DS pipe:
// ds_read of iter k completes before ds_write of iter k+1 overwrites).
//
// Grid: 4096 identical blocks (16 i-chunks' worth per j-slab), 16.6 KB LDS
// -> 8 blocks/CU, no barriers anywhere.

#define NROWS 2048u
#define ICHUNK 16u
#define JSLAB 16u                        // j-rows per wave
#define SLAB_FLOATS (JSLAB * 65u)        // 1040 floats = 4160 B
#define SLAB_F4 (SLAB_FLOATS / 4u)       // 260
#define ROW_F4 (NROWS * 65u / 4u)        // 33280 f4 per i-row-block

typedef float f32x4 __attribute__((ext_vector_type(4)));

__global__ __launch_bounds__(256) void expand_reuse(
    const float* __restrict__ emb,   // [2048*32]
    const float* __restrict__ sw,    // [2048]
    f32x4* __restrict__ out)         // flat output as float4
{
    __shared__ __align__(16) float lds[4][SLAB_FLOATS];   // 16,640 B

    const unsigned tid  = threadIdx.x;
    const unsigned wave = tid >> 6;
    const unsigned lane = tid & 63u;

    // blockIdx -> (i-chunk, j-block). 128 i-chunks x 32 j-blocks = 4096.
    const unsigned bi = blockIdx.x >> 5;          // 0..127
    const unsigned bj = blockIdx.x & 31u;         // 0..31
    const unsigned i0 = bi * ICHUNK;
    const unsigned j0 = bj * 64u + wave * JSLAB;  // wave's 16 j-rows

    float* W = &lds[wave][0];

    // ---- prologue: b-part slab (emb[j0..j0+15], 2 KB) via 2 coalesced f4
    //      wave-loads, scattered into the 65-stride image. Done ONCE.
    {
        const f32x4* ej = (const f32x4*)(emb + (size_t)j0 * 32u);
        const f32x4 b0 = ej[lane];
        const f32x4 b1 = ej[lane + 64u];
        const unsigned d0 = (lane >> 3) * 65u + 32u + (lane & 7u) * 4u;
        W[d0 + 0u] = b0.x; W[d0 + 1u] = b0.y;
        W[d0 + 2u] = b0.z; W[d0 + 3u] = b0.w;
        W[d0 + 520u + 0u] = b1.x; W[d0 + 520u + 1u] = b1.y;
        W[d0 + 520u + 2u] = b1.z; W[d0 + 520u + 3u] = b1.w;
        if (lane < JSLAB) W[lane * 65u + 64u] = sw[j0 + lane];
    }

    // ---- prologue: a-part values for all 16 i's of the chunk.
    //      va[k] = emb[i0+k][lane&31] (128 B wave-broadcast loads, L1/L2-hot).
    float va[ICHUNK];
#pragma unroll
    for (unsigned k = 0; k < ICHUNK; ++k)
        va[k] = emb[(i0 + k) * 32u + (lane & 31u)];

    // a-part scatter geometry: lanes 0-31 rows 0-7, lanes 32-63 rows 8-15,
    // col = lane&31.
    const unsigned rbase = (lane >> 5) * 8u;
    const unsigned c     = lane & 31u;

    // f4 base of this wave's output for i0:  ((i0*2048 + j0) * 65) / 4.
    unsigned ob = i0 * ROW_F4 + ((j0 * 65u) >> 2);

    const f32x4* L4 = (const f32x4*)W;

    // ---- steady state: 16 iterations, load-free.
#pragma unroll
    for (unsigned k = 0; k < ICHUNK; ++k) {
        // rewrite a-part for i = i0+k (8 ds_write_b32 per lane).
#pragma unroll
        for (unsigned rp = 0; rp < 8u; ++rp)
            W[(rbase + rp) * 65u + c] = va[k];

        // drain 260 f4, unit stride, nontemporal. (Compiler inserts the
        // lgkmcnt waits; DS pipe is in-order per wave so the next iter's
        // ds_writes can't pass these ds_reads.)
#pragma unroll
        for (unsigned p = 0; p < 4u; ++p)
            __builtin_nontemporal_store(L4[p * 64u + lane],
                                        &out[ob + p * 64u + lane]);
        if (lane < 4u)
            __builtin_nontemporal_store(L4[256u + lane],
                                        &out[ob + 256u + lane]);

        ob += ROW_F4;
    }
}

extern "C" void kernel_launch(void* const* d_in, const int* in_sizes, int n_in,
                              void* d_out, int out_size, void* d_ws, size_t ws_size,
                              hipStream_t stream) {
    const float* emb = (const float*)d_in[0];   // [2048, 32] f32
    const float* sw  = (const float*)d_in[1];   // [2048] f32
    f32x4* out       = (f32x4*)d_out;

    const unsigned blocks = (NROWS / ICHUNK) * (NROWS / 64u);   // 4096
    expand_reuse<<<dim3(blocks), dim3(256), 0, stream>>>(emb, sw, out);
}

// Round 7
// 203.920 us; speedup vs baseline: 1.1158x; 1.1158x over previous
//
#include <hip/hip_runtime.h>

// n=2048 rows, f=32 features. Output row r = [emb[i] (32) | emb[j] (32) | sw[j]],
// i = r>>11, j = r&2047. Output = 2048*2048*65 floats = 1.09 GB, write-BW bound.
//
// v5: exactly v3 (intra-wave pipelined, double-buffered LDS, no syncs) with
// ONE change: plain stores instead of __builtin_nontemporal_store.
// (Resubmit — round 6 bench died with UnresponsiveContainer; never measured.)
// Rationale: v2b/v3/v4 (three different schedules, all nt) cluster at
// 4.8-5.3 TB/s while fillBufferAligned sustains 6.5 TB/s at LOWER occupancy.
// Occupancy/loads/barriers exonerated; `nt` has never been A/B'd (it was
// introduced together with the barrier removal). Hypothesis: nt streaming
// stores bypass L2 write-combining on gfx950 and tax write efficiency ~20%.

#define NROWS 2048u
#define BLOCK_ROWS 512u                 // per block (4 waves x 128 rows)
#define WAVE_ROWS 128u                  // per wave
#define SLAB_ROWS 16u
#define NSLABS 8u                       // 128/16
#define SLAB_FLOATS (SLAB_ROWS * 65u)   // 1040 floats = 4160 B
#define SLAB_F4 (SLAB_FLOATS / 4u)      // 260 float4, exact

typedef float f32x4 __attribute__((ext_vector_type(4)));

__global__ __launch_bounds__(256) void expand_pipe(
    const float* __restrict__ emb,   // [2048*32]
    const float* __restrict__ sw,    // [2048]
    f32x4* __restrict__ out)         // flat output as float4
{
    __shared__ __align__(16) float lds[4][2][SLAB_FLOATS];   // 33,280 B

    const unsigned tid  = threadIdx.x;
    const unsigned wave = tid >> 6;
    const unsigned lane = tid & 63u;

    // Wave's first output row. 128-aligned, 128 | 2048 -> i constant for the
    // whole wave, j-range j0..j0+127 contiguous (never wraps).
    const unsigned r0 = blockIdx.x * BLOCK_ROWS + wave * WAVE_ROWS;
    const unsigned i  = r0 >> 11;
    const unsigned j0 = r0 & (NROWS - 1u);

    // ---- prologue: a-part. emb[i] is constant for all 128 rows: write cols
    // 0..31 of all 16 slab-rows into BOTH buffers once. Lanes 0-31 rows 0-7,
    // lanes 32-63 rows 8-15, col = lane&31.
    const float vi = emb[i * 32u + (lane & 31u)];
    const unsigned rbase = (lane >> 5) * 8u;
#pragma unroll
    for (unsigned b = 0; b < 2u; ++b)
#pragma unroll
        for (unsigned rp = 0; rp < 8u; ++rp)
            lds[wave][b][(rbase + rp) * 65u + (lane & 31u)] = vi;

    // Static scatter destination for the b-part: global f4 index g in the
    // 128-f4 slab maps to LDS float addr (g>>3)*65 + 32 + (g&7)*4.
    // For g = lane+64 the addr is just d0 + 8*65.
    const unsigned d0 = (lane >> 3) * 65u + 32u + (lane & 7u) * 4u;

    // ---- prologue: prefetch + scatter slab 0 into buffer 0.
    {
        const f32x4* ej = (const f32x4*)(emb + (size_t)j0 * 32u);
        const f32x4 pa = ej[lane];
        const f32x4 pb = ej[lane + 64u];
        const float ps = sw[j0 + (lane & 15u)];
        float* B = &lds[wave][0][0];
        B[d0 + 0u] = pa.x; B[d0 + 1u] = pa.y;
        B[d0 + 2u] = pa.z; B[d0 + 3u] = pa.w;
        B[d0 + 520u + 0u] = pb.x; B[d0 + 520u + 1u] = pb.y;
        B[d0 + 520u + 2u] = pb.z; B[d0 + 520u + 3u] = pb.w;
        if (lane < 16u) B[lane * 65u + 64u] = ps;
    }

    // ---- pipelined main loop over 8 slabs (fully unrolled, static buffers).
#pragma unroll
    for (unsigned s = 0; s < NSLABS; ++s) {
        const unsigned cur = s & 1u;

        // prefetch slab s+1 -> registers (independent of the drain below;
        // scheduler hoists the loads so latency hides under the stores)
        f32x4 pa, pb;
        float ps = 0.0f;
        if (s + 1u < NSLABS) {
            const f32x4* ej =
                (const f32x4*)(emb + (size_t)(j0 + (s + 1u) * SLAB_ROWS) * 32u);
            pa = ej[lane];
            pb = ej[lane + 64u];
            ps = sw[j0 + (s + 1u) * SLAB_ROWS + (lane & 15u)];
        }

        // drain buffer `cur` (slab s): 260 float4, unit stride, plain stores.
        const f32x4* L4 = (const f32x4*)&lds[wave][cur][0];
        const unsigned obase = ((r0 + s * SLAB_ROWS) >> 4) * SLAB_F4;
#pragma unroll
        for (unsigned p = 0; p < 4u; ++p)
            out[obase + p * 64u + lane] = L4[p * 64u + lane];
        if (lane < 4u)
            out[obase + 256u + lane] = L4[256u + lane];

        // scatter prefetched slab s+1 into the other buffer.
        if (s + 1u < NSLABS) {
            float* B = &lds[wave][cur ^ 1u][0];
            B[d0 + 0u] = pa.x; B[d0 + 1u] = pa.y;
            B[d0 + 2u] = pa.z; B[d0 + 3u] = pa.w;
            B[d0 + 520u + 0u] = pb.x; B[d0 + 520u + 1u] = pb.y;
            B[d0 + 520u + 2u] = pb.z; B[d0 + 520u + 3u] = pb.w;
            if (lane < 16u) B[lane * 65u + 64u] = ps;
        }
    }
}

extern "C" void kernel_launch(void* const* d_in, const int* in_sizes, int n_in,
                              void* d_out, int out_size, void* d_ws, size_t ws_size,
                              hipStream_t stream) {
    const float* emb = (const float*)d_in[0];   // [2048, 32] f32
    const float* sw  = (const float*)d_in[1];   // [2048] f32
    f32x4* out       = (f32x4*)d_out;

    const unsigned blocks = (NROWS * NROWS) / BLOCK_ROWS;   // 8192
    expand_pipe<<<dim3(blocks), dim3(256), 0, stream>>>(emb, sw, out);
}